// Round 1
// baseline (303.812 us; speedup 1.0000x reference)
//
#include <hip/hip_runtime.h>
#include <hip/hip_bf16.h>

// ---------------- Kernel A: node embed + soft-proto + mean ----------------
// one block per (sample, branch). LDS-staged, fp32.
__global__ __launch_bounds__(256) void node_kernel(
    const float* __restrict__ fcn, const float* __restrict__ scn,
    const float* __restrict__ Wn, const float* __restrict__ bn,
    const float* __restrict__ Pn,
    float* __restrict__ R, float* __restrict__ nmmean)
{
  __shared__ __align__(16) float sX[8100];      // x [90][90]
  __shared__ __align__(16) float sW[90*48];     // W_node
  __shared__ __align__(16) float sP[64*48];     // P_node row-major
  __shared__ __align__(16) float sPt[48*68];    // P_node transposed [j][p], padded
  __shared__ __align__(16) float sN[90*52];     // nodes / nm (reused), padded
  __shared__ __align__(16) float sS[90*68];     // scores -> weights, padded
  __shared__ __align__(16) float sB[48];

  const int tid = threadIdx.x;
  const int b = blockIdx.x, br = blockIdx.y;
  const float* x = (br ? scn : fcn) + (size_t)b * 8100;

  for (int i = tid; i < 8100; i += 256) sX[i] = x[i];
  for (int i = tid; i < 4320; i += 256) sW[i] = Wn[i];
  for (int i = tid; i < 3072; i += 256) {
    float v = Pn[i];
    sP[i] = v;
    int p = i / 48, j = i - p * 48;
    sPt[j * 68 + p] = v;
  }
  if (tid < 48) sB[tid] = bn[tid];
  __syncthreads();

  // nodes = x @ Wn + bn  -> sN[90][52]
  for (int u = tid; u < 540; u += 256) {
    int i2 = u / 12, j4 = (u - i2 * 12) * 4;
    int i0 = i2 * 2, i1 = i0 + 1;
    float a00 = sB[j4], a01 = sB[j4 + 1], a02 = sB[j4 + 2], a03 = sB[j4 + 3];
    float a10 = a00, a11 = a01, a12 = a02, a13 = a03;
    const float* x0 = &sX[i0 * 90];
    const float* x1 = &sX[i1 * 90];
    #pragma unroll 6
    for (int k = 0; k < 90; ++k) {
      float xv0 = x0[k], xv1 = x1[k];
      float4 wv = *(const float4*)&sW[k * 48 + j4];
      a00 = fmaf(xv0, wv.x, a00); a01 = fmaf(xv0, wv.y, a01);
      a02 = fmaf(xv0, wv.z, a02); a03 = fmaf(xv0, wv.w, a03);
      a10 = fmaf(xv1, wv.x, a10); a11 = fmaf(xv1, wv.y, a11);
      a12 = fmaf(xv1, wv.z, a12); a13 = fmaf(xv1, wv.w, a13);
    }
    *(float4*)&sN[i0 * 52 + j4] = make_float4(a00, a01, a02, a03);
    *(float4*)&sN[i1 * 52 + j4] = make_float4(a10, a11, a12, a13);
  }
  __syncthreads();

  // scores s[i][p] = sum_j P[p][j]*(2*n[i][j] - P[p][j])
  // (== -d2 + ||n_i||^2, a row-constant shift: softmax-invariant)
  for (int u = tid; u < 720; u += 256) {
    int i2 = u >> 4, p4 = (u & 15) * 4;
    int i0 = i2 * 2, i1 = i0 + 1;
    const float* n0 = &sN[i0 * 52];
    const float* n1 = &sN[i1 * 52];
    float s00 = 0, s01 = 0, s02 = 0, s03 = 0;
    float s10 = 0, s11 = 0, s12 = 0, s13 = 0;
    #pragma unroll 8
    for (int j = 0; j < 48; ++j) {
      float4 pv = *(const float4*)&sPt[j * 68 + p4];
      float nv0 = 2.f * n0[j], nv1 = 2.f * n1[j];
      s00 += pv.x * (nv0 - pv.x); s01 += pv.y * (nv0 - pv.y);
      s02 += pv.z * (nv0 - pv.z); s03 += pv.w * (nv0 - pv.w);
      s10 += pv.x * (nv1 - pv.x); s11 += pv.y * (nv1 - pv.y);
      s12 += pv.z * (nv1 - pv.z); s13 += pv.w * (nv1 - pv.w);
    }
    *(float4*)&sS[i0 * 68 + p4] = make_float4(s00, s01, s02, s03);
    *(float4*)&sS[i1 * 68 + p4] = make_float4(s10, s11, s12, s13);
  }
  __syncthreads();

  // per-row softmax over 64 prototypes
  if (tid < 90) {
    float* row = &sS[tid * 68];
    float m = row[0];
    for (int p = 1; p < 64; ++p) m = fmaxf(m, row[p]);
    float sum = 0.f;
    for (int p = 0; p < 64; ++p) { float e = __expf(row[p] - m); row[p] = e; sum += e; }
    float inv = 1.f / sum;
    for (int p = 0; p < 64; ++p) row[p] *= inv;
  }
  __syncthreads();

  // nm = w @ P -> R (and sN for the mean)
  float* Rrow = R + (size_t)b * 8736 + (size_t)br * 4320;
  for (int u = tid; u < 540; u += 256) {
    int i2 = u / 12, j4 = (u - i2 * 12) * 4;
    int i0 = i2 * 2, i1 = i0 + 1;
    const float* w0 = &sS[i0 * 68];
    const float* w1 = &sS[i1 * 68];
    float a00 = 0, a01 = 0, a02 = 0, a03 = 0, a10 = 0, a11 = 0, a12 = 0, a13 = 0;
    #pragma unroll 8
    for (int p = 0; p < 64; ++p) {
      float4 pv = *(const float4*)&sP[p * 48 + j4];
      float wv0 = w0[p], wv1 = w1[p];
      a00 = fmaf(wv0, pv.x, a00); a01 = fmaf(wv0, pv.y, a01);
      a02 = fmaf(wv0, pv.z, a02); a03 = fmaf(wv0, pv.w, a03);
      a10 = fmaf(wv1, pv.x, a10); a11 = fmaf(wv1, pv.y, a11);
      a12 = fmaf(wv1, pv.z, a12); a13 = fmaf(wv1, pv.w, a13);
    }
    *(float4*)&sN[i0 * 52 + j4] = make_float4(a00, a01, a02, a03);
    *(float4*)&sN[i1 * 52 + j4] = make_float4(a10, a11, a12, a13);
    *(float4*)&Rrow[i0 * 48 + j4] = make_float4(a00, a01, a02, a03);
    *(float4*)&Rrow[i1 * 48 + j4] = make_float4(a10, a11, a12, a13);
  }
  __syncthreads();

  if (tid < 48) {
    float s = 0.f;
    for (int i = 0; i < 90; ++i) s += sN[i * 52 + tid];
    nmmean[((size_t)br * 1024 + b) * 48 + tid] = s * (1.f / 90.f);
  }
}

// ---------------- Kernel B: graph-level tiny MLPs + soft-protos ----------------
// one wave per (branch, sample); 4 waves per block.
__global__ __launch_bounds__(256) void graph_kernel(
    const float* __restrict__ nmmean,
    const float* __restrict__ Wg, const float* __restrict__ bg,
    const float* __restrict__ Pg,
    const float* __restrict__ Wg1, const float* __restrict__ bg1,
    const float* __restrict__ Wg2, const float* __restrict__ bg2,
    const float* __restrict__ Pc,
    float* __restrict__ R)
{
  __shared__ float sE[4][64];
  __shared__ float sT[4][64];
  const int tid = threadIdx.x;
  const int wid = tid >> 6, lane = tid & 63;
  const int idx = blockIdx.x * 4 + wid;   // 0..2047
  const int br = idx >> 10, b = idx & 1023;
  const float* mrow = nmmean + (size_t)idx * 48;
  float* Rrow = R + (size_t)b * 8736;

  // eg = mean @ W_graph + b_graph
  if (lane < 32) {
    float e = bg[lane];
    #pragma unroll
    for (int k = 0; k < 48; ++k) e = fmaf(mrow[k], Wg[k * 32 + lane], e);
    sE[wid][lane] = e;
  }
  __syncthreads();
  // soft-proto over P_graph (32 protos, dim 32)
  if (lane < 32) {
    float s = 0.f;
    #pragma unroll
    for (int j = 0; j < 32; ++j) { float pv = Pg[lane * 32 + j]; s += pv * (2.f * sE[wid][j] - pv); }
    float m = s;
    for (int d = 16; d >= 1; d >>= 1) m = fmaxf(m, __shfl_xor(m, d, 64));
    float ex = __expf(s - m);
    float sum = ex;
    for (int d = 16; d >= 1; d >>= 1) sum += __shfl_xor(sum, d, 64);
    sT[wid][lane] = ex / sum;
  }
  __syncthreads();
  if (lane < 32) {
    float g = 0.f;
    #pragma unroll
    for (int p = 0; p < 32; ++p) g = fmaf(sT[wid][p], Pg[p * 32 + lane], g);
    Rrow[8640 + br * 32 + lane] = g;
    sE[wid][lane] = g;
  }
  __syncthreads();
  // h = relu(gp @ Wg1 + bg1)
  if (lane < 32) {
    float h = bg1[lane];
    #pragma unroll
    for (int k = 0; k < 32; ++k) h = fmaf(sE[wid][k], Wg1[k * 32 + lane], h);
    sT[wid][lane] = fmaxf(h, 0.f);
  }
  __syncthreads();
  // ec = h @ Wg2 + bg2
  if (lane < 16) {
    float c = bg2[lane];
    #pragma unroll
    for (int k = 0; k < 32; ++k) c = fmaf(sT[wid][k], Wg2[k * 16 + lane], c);
    sE[wid][lane] = c;
  }
  __syncthreads();
  // soft-proto over P_cls (16 protos, dim 16)
  if (lane < 16) {
    float s = 0.f;
    #pragma unroll
    for (int j = 0; j < 16; ++j) { float pv = Pc[lane * 16 + j]; s += pv * (2.f * sE[wid][j] - pv); }
    float m = s;
    for (int d = 8; d >= 1; d >>= 1) m = fmaxf(m, __shfl_xor(m, d, 64));
    float ex = __expf(s - m);
    float sum = ex;
    for (int d = 8; d >= 1; d >>= 1) sum += __shfl_xor(sum, d, 64);
    sT[wid][lane] = ex / sum;
  }
  __syncthreads();
  if (lane < 16) {
    float c = 0.f;
    #pragma unroll
    for (int p = 0; p < 16; ++p) c = fmaf(sT[wid][p], Pc[p * 16 + lane], c);
    Rrow[8704 + br * 16 + lane] = c;
  }
}

// ---------------- Kernel C: split-K fp32 GEMM  H_part = R @ Wc1 ----------------
// M=1024, N=256, K=8736. BM=BN=64, BK=32, KS=4 (chunks 2208,2176,2176,2176).
__global__ __launch_bounds__(256) void gemm1_kernel(
    const float* __restrict__ R, const float* __restrict__ Wc1,
    float* __restrict__ part)
{
  __shared__ __align__(16) float sA[32 * 68];   // [k][r] transposed A tile
  __shared__ __align__(16) float sBt[32 * 68];  // [k][c] B tile
  const int tid = threadIdx.x;
  const int bm = blockIdx.x * 64, bnc = blockIdx.y * 64, z = blockIdx.z;
  const int kbeg = z * 2176 + (z ? 32 : 0);
  const int klen = z ? 2176 : 2208;
  const int tx = tid & 15, ty = tid >> 4;
  const int la_k = tid & 31, la_r = tid >> 5;
  const int lb_c = tid & 63, lb_k = tid >> 6;
  float acc[4][4] = {{0.f}};
  for (int kk = kbeg; kk < kbeg + klen; kk += 32) {
    #pragma unroll
    for (int r = 0; r < 64; r += 8)
      sA[la_k * 68 + la_r + r] = R[(size_t)(bm + la_r + r) * 8736 + kk + la_k];
    #pragma unroll
    for (int k = 0; k < 32; k += 4)
      sBt[(lb_k + k) * 68 + lb_c] = Wc1[(size_t)(kk + lb_k + k) * 256 + bnc + lb_c];
    __syncthreads();
    #pragma unroll
    for (int k = 0; k < 32; ++k) {
      float4 av = *(const float4*)&sA[k * 68 + ty * 4];
      float4 bv = *(const float4*)&sBt[k * 68 + tx * 4];
      acc[0][0] = fmaf(av.x, bv.x, acc[0][0]);
      acc[0][1] = fmaf(av.x, bv.y, acc[0][1]);
      acc[0][2] = fmaf(av.x, bv.z, acc[0][2]);
      acc[0][3] = fmaf(av.x, bv.w, acc[0][3]);
      acc[1][0] = fmaf(av.y, bv.x, acc[1][0]);
      acc[1][1] = fmaf(av.y, bv.y, acc[1][1]);
      acc[1][2] = fmaf(av.y, bv.z, acc[1][2]);
      acc[1][3] = fmaf(av.y, bv.w, acc[1][3]);
      acc[2][0] = fmaf(av.z, bv.x, acc[2][0]);
      acc[2][1] = fmaf(av.z, bv.y, acc[2][1]);
      acc[2][2] = fmaf(av.z, bv.z, acc[2][2]);
      acc[2][3] = fmaf(av.z, bv.w, acc[2][3]);
      acc[3][0] = fmaf(av.w, bv.x, acc[3][0]);
      acc[3][1] = fmaf(av.w, bv.y, acc[3][1]);
      acc[3][2] = fmaf(av.w, bv.z, acc[3][2]);
      acc[3][3] = fmaf(av.w, bv.w, acc[3][3]);
    }
    __syncthreads();
  }
  float* pz = part + (size_t)z * 262144;
  #pragma unroll
  for (int m = 0; m < 4; ++m) {
    *(float4*)&pz[(size_t)(bm + ty * 4 + m) * 256 + bnc + tx * 4] =
        make_float4(acc[m][0], acc[m][1], acc[m][2], acc[m][3]);
  }
}

// ---------------- Kernel D: reduce K-partials + relu + [256->3] head ----------------
__global__ __launch_bounds__(256) void head_kernel(
    const float* __restrict__ part, const float* __restrict__ bc1,
    const float* __restrict__ Wc2, const float* __restrict__ bc2,
    float* __restrict__ out)
{
  __shared__ float red[3][4];
  const int b = blockIdx.x, t = threadIdx.x;
  float acc = bc1[t];
  #pragma unroll
  for (int z = 0; z < 4; ++z) acc += part[(size_t)z * 262144 + (size_t)b * 256 + t];
  float h = fmaxf(acc, 0.f);
  float p0 = h * Wc2[t * 3 + 0];
  float p1 = h * Wc2[t * 3 + 1];
  float p2 = h * Wc2[t * 3 + 2];
  for (int d = 32; d >= 1; d >>= 1) {
    p0 += __shfl_xor(p0, d, 64);
    p1 += __shfl_xor(p1, d, 64);
    p2 += __shfl_xor(p2, d, 64);
  }
  const int wid = t >> 6, lane = t & 63;
  if (lane == 0) { red[0][wid] = p0; red[1][wid] = p1; red[2][wid] = p2; }
  __syncthreads();
  if (t < 3) {
    out[(size_t)b * 3 + t] = red[t][0] + red[t][1] + red[t][2] + red[t][3] + bc2[t];
  }
}

extern "C" void kernel_launch(void* const* d_in, const int* in_sizes, int n_in,
                              void* d_out, int out_size, void* d_ws, size_t ws_size,
                              hipStream_t stream) {
  const float* fcn     = (const float*)d_in[0];
  const float* scn     = (const float*)d_in[1];
  const float* W_node  = (const float*)d_in[2];
  const float* b_node  = (const float*)d_in[3];
  const float* P_node  = (const float*)d_in[4];
  const float* W_graph = (const float*)d_in[5];
  const float* b_graph = (const float*)d_in[6];
  const float* P_graph = (const float*)d_in[7];
  const float* Wg1     = (const float*)d_in[8];
  const float* bg1     = (const float*)d_in[9];
  const float* Wg2     = (const float*)d_in[10];
  const float* bg2     = (const float*)d_in[11];
  const float* P_cls   = (const float*)d_in[12];
  const float* Wc1     = (const float*)d_in[13];
  const float* bc1     = (const float*)d_in[14];
  const float* Wc2     = (const float*)d_in[15];
  const float* bc2     = (const float*)d_in[16];
  float* out = (float*)d_out;

  float* ws = (float*)d_ws;
  float* R      = ws;                        // 1024*8736 = 8,945,664 floats
  float* nmmean = ws + 8945664;              // 2*1024*48 =    98,304 floats
  float* part   = ws + 8945664 + 98304;      // 4*1024*256 = 1,048,576 floats

  node_kernel<<<dim3(1024, 2), 256, 0, stream>>>(fcn, scn, W_node, b_node, P_node, R, nmmean);
  graph_kernel<<<512, 256, 0, stream>>>(nmmean, W_graph, b_graph, P_graph,
                                        Wg1, bg1, Wg2, bg2, P_cls, R);
  gemm1_kernel<<<dim3(16, 4, 4), 256, 0, stream>>>(R, Wc1, part);
  head_kernel<<<1024, 256, 0, stream>>>(part, bc1, Wc2, bc2, out);
}

// Round 2
// 218.834 us; speedup vs baseline: 1.3883x; 1.3883x over previous
//
#include <hip/hip_runtime.h>
#include <hip/hip_bf16.h>

// ---------------- Kernel P: one-time prep: P_node transpose + row norms ----------------
__global__ __launch_bounds__(256) void prep_kernel(
    const float* __restrict__ Pn, float* __restrict__ Pt, float* __restrict__ q)
{
  const int t = threadIdx.x;
  // Pt[j][p] = Pn[p][j]  (48 x 64)
  for (int i = t; i < 3072; i += 256) {
    int j = i >> 6, p = i & 63;
    Pt[i] = Pn[p * 48 + j];
  }
  if (t < 64) {
    float s = 0.f;
    #pragma unroll
    for (int j = 0; j < 48; ++j) { float v = Pn[t * 48 + j]; s = fmaf(v, v, s); }
    q[t] = s;
  }
}

// ---------------- Kernel A: node embed + soft-proto + mean ----------------
// one block (512 threads) per (sample, branch). LDS = 76.7 KB -> 2 blocks/CU.
// Weights (Wn, bn, Pn, Pt, q) read from global: block-invariant -> L1 resident.
__global__ __launch_bounds__(512) void node_kernel(
    const float* __restrict__ fcn, const float* __restrict__ scn,
    const float* __restrict__ Wn, const float* __restrict__ bn,
    const float* __restrict__ Pn, const float* __restrict__ Ptg,
    const float* __restrict__ qg,
    float* __restrict__ R, float* __restrict__ nmmean)
{
  __shared__ __align__(16) float sX[90 * 92];   // x, row-padded to 92
  __shared__ __align__(16) float sN[90 * 52];   // nodes, then nm (reused)
  __shared__ __align__(16) float sS[90 * 68];   // scores -> weights
  __shared__ float sMean[96];

  const int tid = threadIdx.x;
  const int b = blockIdx.x, br = blockIdx.y;
  const float* x = (br ? scn : fcn) + (size_t)b * 8100;

  // stage x (16B coalesced; 8100*4 bytes per sample keeps 16B alignment)
  for (int i4 = tid; i4 < 2025; i4 += 512) {
    float4 v = *(const float4*)&x[i4 * 4];
    const float vv[4] = {v.x, v.y, v.z, v.w};
    #pragma unroll
    for (int e = 0; e < 4; ++e) {
      int idx = i4 * 4 + e;
      int r = idx / 90, c = idx - r * 90;
      sX[r * 92 + c] = vv[e];
    }
  }
  __syncthreads();

  // ---- embed: nodes = x @ Wn + bn -> sN[90][52] ----
  for (int u = tid; u < 540; u += 512) {
    int i2 = u / 12, j4 = (u - i2 * 12) * 4;
    int i0 = i2 * 2, i1 = i0 + 1;
    float4 bv = *(const float4*)&bn[j4];
    float a00 = bv.x, a01 = bv.y, a02 = bv.z, a03 = bv.w;
    float a10 = bv.x, a11 = bv.y, a12 = bv.z, a13 = bv.w;
    const float* x0 = &sX[i0 * 92];
    const float* x1 = &sX[i1 * 92];
    #pragma unroll 2
    for (int k = 0; k < 88; k += 4) {
      float4 xv0 = *(const float4*)&x0[k];
      float4 xv1 = *(const float4*)&x1[k];
      const float f0[4] = {xv0.x, xv0.y, xv0.z, xv0.w};
      const float f1[4] = {xv1.x, xv1.y, xv1.z, xv1.w};
      #pragma unroll
      for (int e = 0; e < 4; ++e) {
        float4 wv = *(const float4*)&Wn[(k + e) * 48 + j4];
        a00 = fmaf(f0[e], wv.x, a00); a01 = fmaf(f0[e], wv.y, a01);
        a02 = fmaf(f0[e], wv.z, a02); a03 = fmaf(f0[e], wv.w, a03);
        a10 = fmaf(f1[e], wv.x, a10); a11 = fmaf(f1[e], wv.y, a11);
        a12 = fmaf(f1[e], wv.z, a12); a13 = fmaf(f1[e], wv.w, a13);
      }
    }
    #pragma unroll
    for (int k = 88; k < 90; ++k) {
      float xv0 = x0[k], xv1 = x1[k];
      float4 wv = *(const float4*)&Wn[k * 48 + j4];
      a00 = fmaf(xv0, wv.x, a00); a01 = fmaf(xv0, wv.y, a01);
      a02 = fmaf(xv0, wv.z, a02); a03 = fmaf(xv0, wv.w, a03);
      a10 = fmaf(xv1, wv.x, a10); a11 = fmaf(xv1, wv.y, a11);
      a12 = fmaf(xv1, wv.z, a12); a13 = fmaf(xv1, wv.w, a13);
    }
    *(float4*)&sN[i0 * 52 + j4] = make_float4(a00, a01, a02, a03);
    *(float4*)&sN[i1 * 52 + j4] = make_float4(a10, a11, a12, a13);
  }
  __syncthreads();

  // ---- scores: s[i][p] = 2*(n_i . P_p) - ||P_p||^2  (softmax-equivalent to -d2) ----
  for (int u = tid; u < 720; u += 512) {
    int i2 = u >> 4, p4 = (u & 15) * 4;
    int i0 = i2 * 2, i1 = i0 + 1;
    const float* n0 = &sN[i0 * 52];
    const float* n1 = &sN[i1 * 52];
    float s00 = 0, s01 = 0, s02 = 0, s03 = 0;
    float s10 = 0, s11 = 0, s12 = 0, s13 = 0;
    #pragma unroll 2
    for (int j4 = 0; j4 < 48; j4 += 4) {
      float4 nv0 = *(const float4*)&n0[j4];
      float4 nv1 = *(const float4*)&n1[j4];
      const float f0[4] = {nv0.x, nv0.y, nv0.z, nv0.w};
      const float f1[4] = {nv1.x, nv1.y, nv1.z, nv1.w};
      #pragma unroll
      for (int e = 0; e < 4; ++e) {
        float4 pt = *(const float4*)&Ptg[(j4 + e) * 64 + p4];
        s00 = fmaf(f0[e], pt.x, s00); s01 = fmaf(f0[e], pt.y, s01);
        s02 = fmaf(f0[e], pt.z, s02); s03 = fmaf(f0[e], pt.w, s03);
        s10 = fmaf(f1[e], pt.x, s10); s11 = fmaf(f1[e], pt.y, s11);
        s12 = fmaf(f1[e], pt.z, s12); s13 = fmaf(f1[e], pt.w, s13);
      }
    }
    float4 qv = *(const float4*)&qg[p4];
    *(float4*)&sS[i0 * 68 + p4] = make_float4(
        fmaf(2.f, s00, -qv.x), fmaf(2.f, s01, -qv.y),
        fmaf(2.f, s02, -qv.z), fmaf(2.f, s03, -qv.w));
    *(float4*)&sS[i1 * 68 + p4] = make_float4(
        fmaf(2.f, s10, -qv.x), fmaf(2.f, s11, -qv.y),
        fmaf(2.f, s12, -qv.z), fmaf(2.f, s13, -qv.w));
  }
  __syncthreads();

  // ---- softmax over 64 protos; 2 threads/row, pair-exchange via shfl ----
  if (tid < 180) {
    int row = tid >> 1, h = tid & 1;
    float* rp = &sS[row * 68 + h * 32];
    float4 v[8];
    #pragma unroll
    for (int c = 0; c < 8; ++c) v[c] = *(const float4*)&rp[c * 4];
    float m = v[0].x;
    #pragma unroll
    for (int c = 0; c < 8; ++c) {
      m = fmaxf(m, fmaxf(fmaxf(v[c].x, v[c].y), fmaxf(v[c].z, v[c].w)));
    }
    m = fmaxf(m, __shfl_xor(m, 1, 64));
    float sum = 0.f;
    #pragma unroll
    for (int c = 0; c < 8; ++c) {
      v[c].x = __expf(v[c].x - m); v[c].y = __expf(v[c].y - m);
      v[c].z = __expf(v[c].z - m); v[c].w = __expf(v[c].w - m);
      sum += (v[c].x + v[c].y) + (v[c].z + v[c].w);
    }
    sum += __shfl_xor(sum, 1, 64);
    float inv = 1.f / sum;
    #pragma unroll
    for (int c = 0; c < 8; ++c) {
      v[c].x *= inv; v[c].y *= inv; v[c].z *= inv; v[c].w *= inv;
      *(float4*)&rp[c * 4] = v[c];
    }
  }
  __syncthreads();

  // ---- nm = w @ P -> R and sN (for mean) ----
  float* Rrow = R + (size_t)b * 8736 + (size_t)br * 4320;
  for (int u = tid; u < 540; u += 512) {
    int i2 = u / 12, j4 = (u - i2 * 12) * 4;
    int i0 = i2 * 2, i1 = i0 + 1;
    const float* w0 = &sS[i0 * 68];
    const float* w1 = &sS[i1 * 68];
    float a00 = 0, a01 = 0, a02 = 0, a03 = 0, a10 = 0, a11 = 0, a12 = 0, a13 = 0;
    #pragma unroll 2
    for (int p4 = 0; p4 < 64; p4 += 4) {
      float4 wv0 = *(const float4*)&w0[p4];
      float4 wv1 = *(const float4*)&w1[p4];
      const float f0[4] = {wv0.x, wv0.y, wv0.z, wv0.w};
      const float f1[4] = {wv1.x, wv1.y, wv1.z, wv1.w};
      #pragma unroll
      for (int e = 0; e < 4; ++e) {
        float4 pv = *(const float4*)&Pn[(p4 + e) * 48 + j4];
        a00 = fmaf(f0[e], pv.x, a00); a01 = fmaf(f0[e], pv.y, a01);
        a02 = fmaf(f0[e], pv.z, a02); a03 = fmaf(f0[e], pv.w, a03);
        a10 = fmaf(f1[e], pv.x, a10); a11 = fmaf(f1[e], pv.y, a11);
        a12 = fmaf(f1[e], pv.z, a12); a13 = fmaf(f1[e], pv.w, a13);
      }
    }
    *(float4*)&sN[i0 * 52 + j4] = make_float4(a00, a01, a02, a03);
    *(float4*)&sN[i1 * 52 + j4] = make_float4(a10, a11, a12, a13);
    *(float4*)&Rrow[i0 * 48 + j4] = make_float4(a00, a01, a02, a03);
    *(float4*)&Rrow[i1 * 48 + j4] = make_float4(a10, a11, a12, a13);
  }
  __syncthreads();

  if (tid < 96) {
    int j = tid < 48 ? tid : tid - 48;
    int h = tid < 48 ? 0 : 1;
    float s = 0.f;
    for (int i = h * 45; i < h * 45 + 45; ++i) s += sN[i * 52 + j];
    sMean[tid] = s;
  }
  __syncthreads();
  if (tid < 48) {
    nmmean[((size_t)br * 1024 + b) * 48 + tid] =
        (sMean[tid] + sMean[48 + tid]) * (1.f / 90.f);
  }
}

// ---------------- Kernel B: graph-level tiny MLPs + soft-protos ----------------
__global__ __launch_bounds__(256) void graph_kernel(
    const float* __restrict__ nmmean,
    const float* __restrict__ Wg, const float* __restrict__ bg,
    const float* __restrict__ Pg,
    const float* __restrict__ Wg1, const float* __restrict__ bg1,
    const float* __restrict__ Wg2, const float* __restrict__ bg2,
    const float* __restrict__ Pc,
    float* __restrict__ R)
{
  __shared__ float sE[4][64];
  __shared__ float sT[4][64];
  const int tid = threadIdx.x;
  const int wid = tid >> 6, lane = tid & 63;
  const int idx = blockIdx.x * 4 + wid;
  const int br = idx >> 10, b = idx & 1023;
  const float* mrow = nmmean + (size_t)idx * 48;
  float* Rrow = R + (size_t)b * 8736;

  if (lane < 32) {
    float e = bg[lane];
    #pragma unroll
    for (int k = 0; k < 48; ++k) e = fmaf(mrow[k], Wg[k * 32 + lane], e);
    sE[wid][lane] = e;
  }
  __syncthreads();
  if (lane < 32) {
    float s = 0.f;
    #pragma unroll
    for (int j = 0; j < 32; ++j) { float pv = Pg[lane * 32 + j]; s += pv * (2.f * sE[wid][j] - pv); }
    float m = s;
    for (int d = 16; d >= 1; d >>= 1) m = fmaxf(m, __shfl_xor(m, d, 64));
    float ex = __expf(s - m);
    float sum = ex;
    for (int d = 16; d >= 1; d >>= 1) sum += __shfl_xor(sum, d, 64);
    sT[wid][lane] = ex / sum;
  }
  __syncthreads();
  if (lane < 32) {
    float g = 0.f;
    #pragma unroll
    for (int p = 0; p < 32; ++p) g = fmaf(sT[wid][p], Pg[p * 32 + lane], g);
    Rrow[8640 + br * 32 + lane] = g;
    sE[wid][lane] = g;
  }
  __syncthreads();
  if (lane < 32) {
    float h = bg1[lane];
    #pragma unroll
    for (int k = 0; k < 32; ++k) h = fmaf(sE[wid][k], Wg1[k * 32 + lane], h);
    sT[wid][lane] = fmaxf(h, 0.f);
  }
  __syncthreads();
  if (lane < 16) {
    float c = bg2[lane];
    #pragma unroll
    for (int k = 0; k < 32; ++k) c = fmaf(sT[wid][k], Wg2[k * 16 + lane], c);
    sE[wid][lane] = c;
  }
  __syncthreads();
  if (lane < 16) {
    float s = 0.f;
    #pragma unroll
    for (int j = 0; j < 16; ++j) { float pv = Pc[lane * 16 + j]; s += pv * (2.f * sE[wid][j] - pv); }
    float m = s;
    for (int d = 8; d >= 1; d >>= 1) m = fmaxf(m, __shfl_xor(m, d, 64));
    float ex = __expf(s - m);
    float sum = ex;
    for (int d = 8; d >= 1; d >>= 1) sum += __shfl_xor(sum, d, 64);
    sT[wid][lane] = ex / sum;
  }
  __syncthreads();
  if (lane < 16) {
    float c = 0.f;
    #pragma unroll
    for (int p = 0; p < 16; ++p) c = fmaf(sT[wid][p], Pc[p * 16 + lane], c);
    Rrow[8704 + br * 16 + lane] = c;
  }
}

// ---------------- Kernel C: split-K fp32 GEMM  part_z = R_z @ Wc1_z ----------------
// M=1024, N=256, K=8736 (273 tiles of BK=32). KS chunks, runtime.
__global__ __launch_bounds__(256) void gemm1_kernel(
    const float* __restrict__ R, const float* __restrict__ Wc1,
    float* __restrict__ part, int KS)
{
  __shared__ __align__(16) float sA[32 * 68];
  __shared__ __align__(16) float sBt[32 * 68];
  const int tid = threadIdx.x;
  const int bm = blockIdx.x * 64, bnc = blockIdx.y * 64, z = blockIdx.z;
  const int base = 273 / KS, rem = 273 - base * KS;
  const int t0 = z * base + (z < rem ? z : rem);
  const int nt = base + (z < rem ? 1 : 0);
  const int kbeg = t0 * 32, kend = (t0 + nt) * 32;
  const int tx = tid & 15, ty = tid >> 4;
  const int la_k = tid & 31, la_r = tid >> 5;
  const int lb_c = tid & 63, lb_k = tid >> 6;
  float acc[4][4] = {{0.f}};
  for (int kk = kbeg; kk < kend; kk += 32) {
    #pragma unroll
    for (int r = 0; r < 64; r += 8)
      sA[la_k * 68 + la_r + r] = R[(size_t)(bm + la_r + r) * 8736 + kk + la_k];
    #pragma unroll
    for (int k = 0; k < 32; k += 4)
      sBt[(lb_k + k) * 68 + lb_c] = Wc1[(size_t)(kk + lb_k + k) * 256 + bnc + lb_c];
    __syncthreads();
    #pragma unroll
    for (int k = 0; k < 32; ++k) {
      float4 av = *(const float4*)&sA[k * 68 + ty * 4];
      float4 bv = *(const float4*)&sBt[k * 68 + tx * 4];
      acc[0][0] = fmaf(av.x, bv.x, acc[0][0]);
      acc[0][1] = fmaf(av.x, bv.y, acc[0][1]);
      acc[0][2] = fmaf(av.x, bv.z, acc[0][2]);
      acc[0][3] = fmaf(av.x, bv.w, acc[0][3]);
      acc[1][0] = fmaf(av.y, bv.x, acc[1][0]);
      acc[1][1] = fmaf(av.y, bv.y, acc[1][1]);
      acc[1][2] = fmaf(av.y, bv.z, acc[1][2]);
      acc[1][3] = fmaf(av.y, bv.w, acc[1][3]);
      acc[2][0] = fmaf(av.z, bv.x, acc[2][0]);
      acc[2][1] = fmaf(av.z, bv.y, acc[2][1]);
      acc[2][2] = fmaf(av.z, bv.z, acc[2][2]);
      acc[2][3] = fmaf(av.z, bv.w, acc[2][3]);
      acc[3][0] = fmaf(av.w, bv.x, acc[3][0]);
      acc[3][1] = fmaf(av.w, bv.y, acc[3][1]);
      acc[3][2] = fmaf(av.w, bv.z, acc[3][2]);
      acc[3][3] = fmaf(av.w, bv.w, acc[3][3]);
    }
    __syncthreads();
  }
  float* pz = part + (size_t)z * 262144;
  #pragma unroll
  for (int m = 0; m < 4; ++m) {
    *(float4*)&pz[(size_t)(bm + ty * 4 + m) * 256 + bnc + tx * 4] =
        make_float4(acc[m][0], acc[m][1], acc[m][2], acc[m][3]);
  }
}

// ---------------- Kernel D: reduce K-partials + relu + [256->3] head ----------------
__global__ __launch_bounds__(256) void head_kernel(
    const float* __restrict__ part, const float* __restrict__ bc1,
    const float* __restrict__ Wc2, const float* __restrict__ bc2,
    float* __restrict__ out, int KS)
{
  __shared__ float red[3][4];
  const int b = blockIdx.x, t = threadIdx.x;
  float acc = bc1[t];
  for (int z = 0; z < KS; ++z) acc += part[(size_t)z * 262144 + (size_t)b * 256 + t];
  float h = fmaxf(acc, 0.f);
  float p0 = h * Wc2[t * 3 + 0];
  float p1 = h * Wc2[t * 3 + 1];
  float p2 = h * Wc2[t * 3 + 2];
  for (int d = 32; d >= 1; d >>= 1) {
    p0 += __shfl_xor(p0, d, 64);
    p1 += __shfl_xor(p1, d, 64);
    p2 += __shfl_xor(p2, d, 64);
  }
  const int wid = t >> 6, lane = t & 63;
  if (lane == 0) { red[0][wid] = p0; red[1][wid] = p1; red[2][wid] = p2; }
  __syncthreads();
  if (t < 3) {
    out[(size_t)b * 3 + t] = red[t][0] + red[t][1] + red[t][2] + red[t][3] + bc2[t];
  }
}

extern "C" void kernel_launch(void* const* d_in, const int* in_sizes, int n_in,
                              void* d_out, int out_size, void* d_ws, size_t ws_size,
                              hipStream_t stream) {
  const float* fcn     = (const float*)d_in[0];
  const float* scn     = (const float*)d_in[1];
  const float* W_node  = (const float*)d_in[2];
  const float* b_node  = (const float*)d_in[3];
  const float* P_node  = (const float*)d_in[4];
  const float* W_graph = (const float*)d_in[5];
  const float* b_graph = (const float*)d_in[6];
  const float* P_graph = (const float*)d_in[7];
  const float* Wg1     = (const float*)d_in[8];
  const float* bg1     = (const float*)d_in[9];
  const float* Wg2     = (const float*)d_in[10];
  const float* bg2     = (const float*)d_in[11];
  const float* P_cls   = (const float*)d_in[12];
  const float* Wc1     = (const float*)d_in[13];
  const float* bc1     = (const float*)d_in[14];
  const float* Wc2     = (const float*)d_in[15];
  const float* bc2     = (const float*)d_in[16];
  float* out = (float*)d_out;

  float* ws = (float*)d_ws;
  float* R      = ws;                                // 8,945,664 floats
  float* nmmean = R + 8945664;                       //    98,304
  float* Pt     = nmmean + 98304;                    //     3,072
  float* q      = Pt + 3072;                         //        64
  float* part   = q + 64;                            // KS * 262,144

  // pick split-K by available workspace (fits KS=8 at ws >= ~44.6 MB)
  const size_t fixed = 8945664 + 98304 + 3072 + 64;
  size_t avail = ws_size / 4 > fixed ? ws_size / 4 - fixed : 0;
  int KS = (int)(avail / 262144);
  if (KS > 8) KS = 8;
  if (KS < 1) KS = 1;

  prep_kernel<<<1, 256, 0, stream>>>(P_node, Pt, q);
  node_kernel<<<dim3(1024, 2), 512, 0, stream>>>(fcn, scn, W_node, b_node,
                                                 P_node, Pt, q, R, nmmean);
  graph_kernel<<<512, 256, 0, stream>>>(nmmean, W_graph, b_graph, P_graph,
                                        Wg1, bg1, Wg2, bg2, P_cls, R);
  gemm1_kernel<<<dim3(16, 4, KS), 256, 0, stream>>>(R, Wc1, part, KS);
  head_kernel<<<1024, 256, 0, stream>>>(part, bc1, Wc2, bc2, out, KS);
}